// Round 7
// baseline (87.821 us; speedup 1.0000x reference)
//
#include <hip/hip_runtime.h>
#include <hip/hip_bf16.h>

// Problem constants
#define B 256
#define S 256
#define H 768
#define C 150
#define H4 192              // H / 4 (float4 columns)

// ws layout (bytes), CH=4:
//  part1   : 0        .. 3145728   [256][4][768] f32 pool partials
//  dp      : 3145728  .. 4374528   [8][256][150] f32 score-dot partials (per col-split)
//  tx_part : 4374528  .. 4382720   [8][256] f32 (per col-split)
//  tm_part : 4382720  .. 4387584   [8][152] f32 (per K-slice)
//  cntp    : 4387584  .. 4391680   [256][4] i32 mask counts
//  ticket  : 4391680  .. 4391808   [32] i32 fan-in tickets (memset 0 each launch)

// ---------------------------------------------------------------------------
// K1: blocks 0..1023   : masked pool partial (b = bid>>2, 64-row chunk bid&3).
//     blocks 1024..1327: t_m partials — 4 means-rows (12KB LDS), k-slice of 96.
// 12 KB LDS keeps pool at 10 blocks/CU; tm blocks run free under HBM phase.
// ---------------------------------------------------------------------------
__global__ __launch_bounds__(192) void kPoolTm(const float* __restrict__ lhs,
                                               const int* __restrict__ mask,
                                               const float* __restrict__ means,
                                               const float* __restrict__ cov,
                                               float* __restrict__ part1,
                                               int* __restrict__ cntp,
                                               float* __restrict__ tm_part) {
    const int bid = blockIdx.x;
    const int t = threadIdx.x;
    __shared__ float shbuf[4 * H];    // 12 KB: msk[64] (pool) / means rows (tm)
    __shared__ float red[4][3];

    if (bid < 1024) {
        // ---- pool partial ----
        const int b = bid >> 2, chunk = bid & 3, s0 = chunk * 64;
        float* msk = shbuf;
        if (t < 64) {
            const int mv = mask[b * S + s0 + t];
            msk[t] = (float)mv;
            int v = mv;
#pragma unroll
            for (int off = 32; off > 0; off >>= 1) v += __shfl_down(v, off, 64);
            if (t == 0) cntp[b * 4 + chunk] = v;
        }
        __syncthreads();

        const float4* src = (const float4*)lhs + (size_t)(b * S + s0) * H4 + t;
        float4 acc = make_float4(0.f, 0.f, 0.f, 0.f);
#pragma unroll 8
        for (int s = 0; s < 64; ++s) {
            const float m = msk[s];
            const float4 v = src[(size_t)s * H4];
            acc.x += v.x * m; acc.y += v.y * m; acc.z += v.z * m; acc.w += v.w * m;
        }
        ((float4*)part1)[(size_t)(b * 4 + chunk) * H4 + t] = acc;
    } else {
        // ---- t_m partial: rows r0..r0+3, k in [ks*96, ks*96+96) ----
        const int idx = bid - 1024;           // 0..303
        const int rg = idx >> 3, ks = idx & 7;
        const int r0 = rg * 4, k0 = ks * 96;

#pragma unroll
        for (int r = 0; r < 4; ++r) {
            const int row = r0 + r;
            float4 v = make_float4(0.f, 0.f, 0.f, 0.f);
            if (row < C) v = ((const float4*)means)[(size_t)row * H4 + t];
            ((float4*)shbuf)[r * H4 + t] = v;
        }
        __syncthreads();

        float4 acc[4];
#pragma unroll
        for (int r = 0; r < 4; ++r) acc[r] = make_float4(0.f, 0.f, 0.f, 0.f);
        const float4* cov4 = (const float4*)cov + t;
#pragma unroll 4
        for (int kk = 0; kk < 96; ++kk) {
            const int k = k0 + kk;
            const float4 cv = cov4[(size_t)k * H4];
#pragma unroll
            for (int r = 0; r < 4; ++r) {
                const float xv = shbuf[r * H + k];
                acc[r].x += xv * cv.x; acc[r].y += xv * cv.y;
                acc[r].z += xv * cv.z; acc[r].w += xv * cv.w;
            }
        }
        const int w = t >> 6;
#pragma unroll
        for (int r = 0; r < 4; ++r) {
            const float4 mu = ((float4*)shbuf)[r * H4 + t];
            float pd = acc[r].x * mu.x + acc[r].y * mu.y + acc[r].z * mu.z + acc[r].w * mu.w;
#pragma unroll
            for (int off = 32; off > 0; off >>= 1) pd += __shfl_down(pd, off, 64);
            if ((t & 63) == 0) red[r][w] = pd;
        }
        __syncthreads();
        if (t < 4) {
            const int row = r0 + t;
            if (row < C)
                tm_part[ks * 152 + row] = red[t][0] + red[t][1] + red[t][2];
        }
    }
}

// ---------------------------------------------------------------------------
// K2: xS col-slice GEMM (pool-finalize inlined) + t_x partials + score-dot
// partials; the LAST col-split block of each row-tile (device-scope ticket)
// then reduces partials in fixed order -> scores + argmin for its 8 rows.
// grid 256 = 32 row-tiles x 8 col-splits, block 192 = 8 kg x 24 f4-cols.
// ---------------------------------------------------------------------------
__global__ __launch_bounds__(192) void kCF(const float* __restrict__ part1,
                                           const int* __restrict__ cntp,
                                           const float* __restrict__ cov,
                                           const float* __restrict__ means,
                                           float* __restrict__ dp,
                                           float* __restrict__ tx_part,
                                           const float* __restrict__ tm_part,
                                           int* __restrict__ ticket,
                                           float* __restrict__ out) {
    const int rt = blockIdx.x >> 3, cs = blockIdx.x & 7;
    const int r0 = rt * 8, cb = cs * 24;
    const int t = threadIdx.x;
    const int kg = t / 24, c4 = t % 24;
    __shared__ float xsl[8 * H];          // 24 KB
    __shared__ float4 red2[8][24];        // 3 KB
    __shared__ float4 xsf[8][24];         // 3 KB
    __shared__ float sv[192];
    __shared__ int si[192];
    __shared__ int winflag;

    // pool finalize into LDS
    for (int r = 0; r < 8; ++r) {
        const int row = r0 + r;
        const int cnt = cntp[row * 4] + cntp[row * 4 + 1] + cntp[row * 4 + 2] + cntp[row * 4 + 3];
        const float inv = 1.0f / fmaxf((float)cnt, 1e-9f);
        const float4* p = (const float4*)part1 + (size_t)row * 4 * H4 + t;
        const float4 a = p[0], b2 = p[H4], c2 = p[2 * H4], d2 = p[3 * H4];
        float4 v;
        v.x = (a.x + b2.x + c2.x + d2.x) * inv;
        v.y = (a.y + b2.y + c2.y + d2.y) * inv;
        v.z = (a.z + b2.z + c2.z + d2.z) * inv;
        v.w = (a.w + b2.w + c2.w + d2.w) * inv;
        ((float4*)xsl)[r * H4 + t] = v;
    }
    __syncthreads();

    float4 acc[8];
#pragma unroll
    for (int r = 0; r < 8; ++r) acc[r] = make_float4(0.f, 0.f, 0.f, 0.f);
    const float4* cov4 = (const float4*)cov + cb + c4;
#pragma unroll 4
    for (int kk = 0; kk < 96; ++kk) {
        const int k = kg * 96 + kk;
        const float4 cv = cov4[(size_t)k * H4];
#pragma unroll
        for (int r = 0; r < 8; ++r) {
            const float xv = xsl[r * H + k];
            acc[r].x += xv * cv.x; acc[r].y += xv * cv.y;
            acc[r].z += xv * cv.z; acc[r].w += xv * cv.w;
        }
    }

    float pdr[8];
#pragma unroll
    for (int r = 0; r < 8; ++r) pdr[r] = 0.f;
    for (int r = 0; r < 8; ++r) {
        red2[kg][c4] = acc[r];
        __syncthreads();
        if (kg == 0) {
            float4 s = red2[0][c4];
#pragma unroll
            for (int g = 1; g < 8; ++g) {
                const float4 q = red2[g][c4];
                s.x += q.x; s.y += q.y; s.z += q.z; s.w += q.w;
            }
            xsf[r][c4] = s;
            const float4 xv = ((float4*)xsl)[r * H4 + cb + c4];
            pdr[r] = s.x * xv.x + s.y * xv.y + s.z * xv.z + s.w * xv.w;
        }
        __syncthreads();
    }

    // t_x partials (lanes 0..23 hold contributions)
    if (t < 64) {
#pragma unroll
        for (int r = 0; r < 8; ++r) {
            float v = (t < 24) ? pdr[r] : 0.f;
#pragma unroll
            for (int off = 16; off > 0; off >>= 1) v += __shfl_down(v, off, 32);
            if (t == 0) tx_part[cs * 256 + r0 + r] = v;
        }
    }

    // score-dot partials: thread t = class c, stream means slice from L2
    if (t < C) {
        const float4* mu4 = (const float4*)means + (size_t)t * H4 + cb;
        float a8[8];
#pragma unroll
        for (int r = 0; r < 8; ++r) a8[r] = 0.f;
#pragma unroll 4
        for (int j = 0; j < 24; ++j) {
            const float4 mv = mu4[j];
#pragma unroll
            for (int r = 0; r < 8; ++r) {
                const float4 x = xsf[r][j];
                a8[r] += mv.x * x.x + mv.y * x.y + mv.z * x.z + mv.w * x.w;
            }
        }
#pragma unroll
        for (int r = 0; r < 8; ++r)
            dp[((size_t)(cs * 256) + (r0 + r)) * 150 + t] = a8[r];
    }

    // ---- fan-in: last arrival of this row-tile finishes scores + argmin ----
    __syncthreads();
    if (t == 0) {
        __threadfence();
        const int old = __hip_atomic_fetch_add(&ticket[rt], 1, __ATOMIC_ACQ_REL,
                                               __HIP_MEMORY_SCOPE_AGENT);
        winflag = (old == 7);
    }
    __syncthreads();
    if (!winflag) return;

    for (int r = 0; r < 8; ++r) {
        const int row = r0 + r;
        float sc = INFINITY;
        if (t < C) {
            float d = 0.f;
#pragma unroll
            for (int j = 0; j < 8; ++j) d += dp[((size_t)(j * 256) + row) * 150 + t];
            float tx = 0.f;
#pragma unroll
            for (int j = 0; j < 8; ++j) tx += tx_part[j * 256 + row];
            float tm = 0.f;
#pragma unroll
            for (int j = 0; j < 8; ++j) tm += tm_part[j * 152 + t];
            sc = tx - 2.0f * d + tm;
            out[B + (size_t)t * B + row] = sc;
        }
        sv[t] = sc;
        si[t] = (t < C) ? t : 0x7fffffff;
        __syncthreads();
#pragma unroll
        for (int off = 96; off >= 3; off >>= 1) {
            if (t < off) {
                const float ov = sv[t + off];
                const int oi = si[t + off];
                if (ov < sv[t] || (ov == sv[t] && oi < si[t])) { sv[t] = ov; si[t] = oi; }
            }
            __syncthreads();
        }
        if (t == 0) {
            float bv = sv[0];
            int bi = si[0];
#pragma unroll
            for (int j = 1; j < 3; ++j)
                if (sv[j] < bv || (sv[j] == bv && si[j] < bi)) { bv = sv[j]; bi = si[j]; }
            out[row] = (float)bi;
        }
        __syncthreads();
    }
}

extern "C" void kernel_launch(void* const* d_in, const int* in_sizes, int n_in,
                              void* d_out, int out_size, void* d_ws, size_t ws_size,
                              hipStream_t stream) {
    const float* lhs   = (const float*)d_in[0];   // [B,S,H] f32
    const int*   mask  = (const int*)d_in[1];     // [B,S] i32
    const float* means = (const float*)d_in[2];   // [C,H] f32
    const float* cov   = (const float*)d_in[3];   // [H,H] f32
    float* out = (float*)d_out;
    char* ws = (char*)d_ws;

    float* part1   = (float*)(ws + 0);
    float* dp      = (float*)(ws + 3145728);
    float* tx_part = (float*)(ws + 4374528);
    float* tm_part = (float*)(ws + 4382720);
    int*   cntp    = (int*)  (ws + 4387584);
    int*   ticket  = (int*)  (ws + 4391680);

    hipMemsetAsync(ticket, 0, 128, stream);
    kPoolTm<<<dim3(1024 + 304), 192, 0, stream>>>(lhs, mask, means, cov, part1, cntp, tm_part);
    kCF<<<dim3(256), 192, 0, stream>>>(part1, cntp, cov, means, dp, tx_part, tm_part, ticket, out);
}

// Round 9
// 61.786 us; speedup vs baseline: 1.4214x; 1.4214x over previous
//
#include <hip/hip_runtime.h>
#include <hip/hip_bf16.h>

// Problem constants
#define B 256
#define S 256
#define H 768
#define C 150
#define H4 192              // H / 4 (float4 columns)

typedef float f32x4 __attribute__((ext_vector_type(4)));

// ws layout (bytes), CH=4:
//  part1   : 0        .. 3145728   [256][4][768] f32 pool partials
//  dp      : 3145728  .. 4374528   [8][256][150] f32 score-dot partials
//  tx_part : 4374528  .. 4382720   [8][256] f32
//  tm_part : 4382720  .. 4387584   [8][152] f32
//  cntp    : 4387584  .. 4391680   [256][4] i32 mask counts

// ---------------------------------------------------------------------------
// kPool: pure masked pool partial. grid 1024 (b = bid>>2, 64-row chunk bid&3),
// block 192, LDS = 256B -> 10 blocks/CU, 30 waves/CU. lhs loads nontemporal
// (read-once stream; don't displace cov/means in L2/L3).
// ---------------------------------------------------------------------------
__global__ __launch_bounds__(192) void kPool(const float* __restrict__ lhs,
                                             const int* __restrict__ mask,
                                             float* __restrict__ part1,
                                             int* __restrict__ cntp) {
    const int bid = blockIdx.x;
    const int t = threadIdx.x;
    __shared__ float msk[64];

    const int b = bid >> 2, chunk = bid & 3, s0 = chunk * 64;
    if (t < 64) {
        const int mv = mask[b * S + s0 + t];
        msk[t] = (float)mv;
        int v = mv;
#pragma unroll
        for (int off = 32; off > 0; off >>= 1) v += __shfl_down(v, off, 64);
        if (t == 0) cntp[b * 4 + chunk] = v;
    }
    __syncthreads();

    const f32x4* src = (const f32x4*)lhs + (size_t)(b * S + s0) * H4 + t;
    f32x4 acc = (f32x4){0.f, 0.f, 0.f, 0.f};
#pragma unroll 8
    for (int s = 0; s < 64; ++s) {
        const float m = msk[s];
        const f32x4 v = __builtin_nontemporal_load(&src[(size_t)s * H4]);
        acc += v * m;
    }
    ((f32x4*)part1)[(size_t)(b * 4 + chunk) * H4 + t] = acc;
}

// ---------------------------------------------------------------------------
// kC: blocks 0..255  : xS col-slice GEMM (pool-finalize inlined) + t_x
//                      partials + score-dot partials vs all 150 means.
//     blocks 256..407: t_m partials (means @ cov . means), no pool dependency.
// block 192 = 8 kg x 24 f4-cols.
// ---------------------------------------------------------------------------
__global__ __launch_bounds__(192) void kC(const float* __restrict__ part1,
                                          const int* __restrict__ cntp,
                                          const float* __restrict__ cov,
                                          const float* __restrict__ means,
                                          float* __restrict__ dp,
                                          float* __restrict__ tx_part,
                                          float* __restrict__ tm_part) {
    const int t = threadIdx.x;
    const int kg = t / 24, c4 = t % 24;
    __shared__ float xsl[8 * H];          // 24 KB
    __shared__ float4 red2[8][24];        // 3 KB
    __shared__ float4 xsf[8][24];         // 3 KB
    __shared__ float sred[8][3];

    if (blockIdx.x < 256) {
        const int rt = blockIdx.x >> 3, cs = blockIdx.x & 7;
        const int r0 = rt * 8, cb = cs * 24;

        // pool finalize into LDS
        for (int r = 0; r < 8; ++r) {
            const int row = r0 + r;
            const int cnt = cntp[row * 4] + cntp[row * 4 + 1] + cntp[row * 4 + 2] + cntp[row * 4 + 3];
            const float inv = 1.0f / fmaxf((float)cnt, 1e-9f);
            const float4* p = (const float4*)part1 + (size_t)row * 4 * H4 + t;
            const float4 a = p[0], b2 = p[H4], c2 = p[2 * H4], d2 = p[3 * H4];
            float4 v;
            v.x = (a.x + b2.x + c2.x + d2.x) * inv;
            v.y = (a.y + b2.y + c2.y + d2.y) * inv;
            v.z = (a.z + b2.z + c2.z + d2.z) * inv;
            v.w = (a.w + b2.w + c2.w + d2.w) * inv;
            ((float4*)xsl)[r * H4 + t] = v;
        }
        __syncthreads();

        float4 acc[8];
#pragma unroll
        for (int r = 0; r < 8; ++r) acc[r] = make_float4(0.f, 0.f, 0.f, 0.f);
        const float4* cov4 = (const float4*)cov + cb + c4;
#pragma unroll 4
        for (int kk = 0; kk < 96; ++kk) {
            const int k = kg * 96 + kk;
            const float4 cv = cov4[(size_t)k * H4];
#pragma unroll
            for (int r = 0; r < 8; ++r) {
                const float xv = xsl[r * H + k];
                acc[r].x += xv * cv.x; acc[r].y += xv * cv.y;
                acc[r].z += xv * cv.z; acc[r].w += xv * cv.w;
            }
        }

        float pdr[8];
#pragma unroll
        for (int r = 0; r < 8; ++r) pdr[r] = 0.f;
        for (int r = 0; r < 8; ++r) {
            red2[kg][c4] = acc[r];
            __syncthreads();
            if (kg == 0) {
                float4 s = red2[0][c4];
#pragma unroll
                for (int g = 1; g < 8; ++g) {
                    const float4 q = red2[g][c4];
                    s.x += q.x; s.y += q.y; s.z += q.z; s.w += q.w;
                }
                xsf[r][c4] = s;
                const float4 xv = ((float4*)xsl)[r * H4 + cb + c4];
                pdr[r] = s.x * xv.x + s.y * xv.y + s.z * xv.z + s.w * xv.w;
            }
            __syncthreads();
        }

        // t_x partials (lanes 0..23 hold contributions)
        if (t < 64) {
#pragma unroll
            for (int r = 0; r < 8; ++r) {
                float v = (t < 24) ? pdr[r] : 0.f;
#pragma unroll
                for (int off = 16; off > 0; off >>= 1) v += __shfl_down(v, off, 32);
                if (t == 0) tx_part[cs * 256 + r0 + r] = v;
            }
        }

        // score-dot partials: thread t = class c, stream means slice from L2
        if (t < C) {
            const float4* mu4 = (const float4*)means + (size_t)t * H4 + cb;
            float a8[8];
#pragma unroll
            for (int r = 0; r < 8; ++r) a8[r] = 0.f;
#pragma unroll 4
            for (int j = 0; j < 24; ++j) {
                const float4 mv = mu4[j];
#pragma unroll
                for (int r = 0; r < 8; ++r) {
                    const float4 x = xsf[r][j];
                    a8[r] += mv.x * x.x + mv.y * x.y + mv.z * x.z + mv.w * x.w;
                }
            }
#pragma unroll
            for (int r = 0; r < 8; ++r)
                dp[((size_t)(cs * 256) + (r0 + r)) * 150 + t] = a8[r];
        }
    } else {
        // ---- t_m partials: rows r0..r0+7 of means, f4-cols cb..cb+23, k-split 8 ----
        const int idx = blockIdx.x - 256;
        const int rt = idx >> 3, cs = idx & 7;
        const int r0 = rt * 8, cb = cs * 24;

        for (int r = 0; r < 8; ++r) {
            const int row = r0 + r;
            float4 v = make_float4(0.f, 0.f, 0.f, 0.f);
            if (row < C) v = ((const float4*)means)[(size_t)row * H4 + t];
            ((float4*)xsl)[r * H4 + t] = v;
        }
        __syncthreads();

        float4 acc[8];
#pragma unroll
        for (int r = 0; r < 8; ++r) acc[r] = make_float4(0.f, 0.f, 0.f, 0.f);
        const float4* cov4 = (const float4*)cov + cb + c4;
#pragma unroll 4
        for (int kk = 0; kk < 96; ++kk) {
            const int k = kg * 96 + kk;
            const float4 cv = cov4[(size_t)k * H4];
#pragma unroll
            for (int r = 0; r < 8; ++r) {
                const float xv = xsl[r * H + k];
                acc[r].x += xv * cv.x; acc[r].y += xv * cv.y;
                acc[r].z += xv * cv.z; acc[r].w += xv * cv.w;
            }
        }
        const int w = t >> 6;
#pragma unroll
        for (int r = 0; r < 8; ++r) {
            const float4 mu = ((float4*)xsl)[r * H4 + cb + c4];
            float pd = acc[r].x * mu.x + acc[r].y * mu.y + acc[r].z * mu.z + acc[r].w * mu.w;
#pragma unroll
            for (int off = 32; off > 0; off >>= 1) pd += __shfl_down(pd, off, 64);
            if ((t & 63) == 0) sred[r][w] = pd;
        }
        __syncthreads();
        if (t < 8) {
            const int row = r0 + t;
            if (row < C)
                tm_part[cs * 152 + row] = sred[t][0] + sred[t][1] + sred[t][2];
        }
    }
}

// ---------------------------------------------------------------------------
// kD: reduce partials -> scores + argmin. One block per b, 192 threads.
// ---------------------------------------------------------------------------
__global__ __launch_bounds__(192) void kD(const float* __restrict__ dp,
                                          const float* __restrict__ tx_part,
                                          const float* __restrict__ tm_part,
                                          float* __restrict__ out) {
    const int b = blockIdx.x, t = threadIdx.x;
    __shared__ float sv[192];
    __shared__ int si[192];

    float sc = INFINITY;
    if (t < C) {
        float d = 0.f;
#pragma unroll
        for (int j = 0; j < 8; ++j) d += dp[((size_t)(j * 256) + b) * 150 + t];
        float tx = 0.f;
#pragma unroll
        for (int j = 0; j < 8; ++j) tx += tx_part[j * 256 + b];
        float tm = 0.f;
#pragma unroll
        for (int j = 0; j < 8; ++j) tm += tm_part[j * 152 + t];
        sc = tx - 2.0f * d + tm;
        out[B + (size_t)t * B + b] = sc;
    }
    sv[t] = sc;
    si[t] = (t < C) ? t : 0x7fffffff;
    __syncthreads();
#pragma unroll
    for (int off = 96; off >= 3; off >>= 1) {
        if (t < off) {
            const float ov = sv[t + off];
            const int oi = si[t + off];
            if (ov < sv[t] || (ov == sv[t] && oi < si[t])) { sv[t] = ov; si[t] = oi; }
        }
        __syncthreads();
    }
    if (t == 0) {
        float bv = sv[0];
        int bi = si[0];
#pragma unroll
        for (int j = 1; j < 3; ++j)
            if (sv[j] < bv || (sv[j] == bv && si[j] < bi)) { bv = sv[j]; bi = si[j]; }
        out[b] = (float)bi;
    }
}

extern "C" void kernel_launch(void* const* d_in, const int* in_sizes, int n_in,
                              void* d_out, int out_size, void* d_ws, size_t ws_size,
                              hipStream_t stream) {
    const float* lhs   = (const float*)d_in[0];   // [B,S,H] f32
    const int*   mask  = (const int*)d_in[1];     // [B,S] i32
    const float* means = (const float*)d_in[2];   // [C,H] f32
    const float* cov   = (const float*)d_in[3];   // [H,H] f32
    float* out = (float*)d_out;
    char* ws = (char*)d_ws;

    float* part1   = (float*)(ws + 0);
    float* dp      = (float*)(ws + 3145728);
    float* tx_part = (float*)(ws + 4374528);
    float* tm_part = (float*)(ws + 4382720);
    int*   cntp    = (int*)  (ws + 4387584);

    kPool<<<dim3(1024), 192, 0, stream>>>(lhs, mask, part1, cntp);
    kC<<<dim3(256 + 152), 192, 0, stream>>>(part1, cntp, cov, means, dp, tx_part, tm_part);
    kD<<<dim3(256), 192, 0, stream>>>(dp, tx_part, tm_part, out);
}

// Round 10
// 59.968 us; speedup vs baseline: 1.4645x; 1.0303x over previous
//
#include <hip/hip_runtime.h>
#include <hip/hip_bf16.h>

// Problem constants
#define B 256
#define S 256
#define H 768
#define C 150
#define H4 192              // H / 4 (float4 columns)

#define NTM 304             // t_m blocks (first in grid, overlap pool phase)

// ws layout (bytes), CH=4:
//  part1   : 0        .. 3145728   [256][4][768] f32 pool partials
//  dp      : 3145728  .. 4374528   [8][256][150] f32 score-dot partials
//  tx_part : 4374528  .. 4382720   [8][256] f32
//  tm_part : 4382720  .. 4387584   [8][152] f32
//  cntp    : 4387584  .. 4391680   [256][4] i32 mask counts

// ---------------------------------------------------------------------------
// kA: blocks 0..303    : t_m partials — 4 means-rows, k-slice of 96 (L2-bound,
//                        runs for free under the HBM-bound pool phase).
//     blocks 304..1327 : masked pool partial (b, 64-row chunk), coalesced
//                        float4 stream. 12.3 KB LDS -> 13 blocks/CU cap.
// ---------------------------------------------------------------------------
__global__ __launch_bounds__(192) void kA(const float* __restrict__ lhs,
                                          const int* __restrict__ mask,
                                          const float* __restrict__ means,
                                          const float* __restrict__ cov,
                                          float* __restrict__ part1,
                                          int* __restrict__ cntp,
                                          float* __restrict__ tm_part) {
    const int bid = blockIdx.x;
    const int t = threadIdx.x;
    __shared__ float shbuf[4 * H];    // 12 KB: msk[64] (pool) / means rows (tm)
    __shared__ float red[4][3];

    if (bid >= NTM) {
        // ---- pool partial ----
        const int pb = bid - NTM;
        const int b = pb >> 2, chunk = pb & 3, s0 = chunk * 64;
        float* msk = shbuf;
        if (t < 64) {
            const int mv = mask[b * S + s0 + t];
            msk[t] = (float)mv;
            int v = mv;
#pragma unroll
            for (int off = 32; off > 0; off >>= 1) v += __shfl_down(v, off, 64);
            if (t == 0) cntp[b * 4 + chunk] = v;
        }
        __syncthreads();

        const float4* src = (const float4*)lhs + (size_t)(b * S + s0) * H4 + t;
        float4 acc = make_float4(0.f, 0.f, 0.f, 0.f);
#pragma unroll 8
        for (int s = 0; s < 64; ++s) {
            const float m = msk[s];
            const float4 v = src[(size_t)s * H4];
            acc.x += v.x * m; acc.y += v.y * m; acc.z += v.z * m; acc.w += v.w * m;
        }
        ((float4*)part1)[(size_t)(b * 4 + chunk) * H4 + t] = acc;
    } else {
        // ---- t_m partial: rows r0..r0+3, k in [ks*96, ks*96+96) ----
        const int rg = bid >> 3, ks = bid & 7;
        const int r0 = rg * 4, k0 = ks * 96;

#pragma unroll
        for (int r = 0; r < 4; ++r) {
            const int row = r0 + r;
            float4 v = make_float4(0.f, 0.f, 0.f, 0.f);
            if (row < C) v = ((const float4*)means)[(size_t)row * H4 + t];
            ((float4*)shbuf)[r * H4 + t] = v;
        }
        __syncthreads();

        float4 acc[4];
#pragma unroll
        for (int r = 0; r < 4; ++r) acc[r] = make_float4(0.f, 0.f, 0.f, 0.f);
        const float4* cov4 = (const float4*)cov + t;
#pragma unroll 4
        for (int kk = 0; kk < 96; ++kk) {
            const int k = k0 + kk;
            const float4 cv = cov4[(size_t)k * H4];
#pragma unroll
            for (int r = 0; r < 4; ++r) {
                const float xv = shbuf[r * H + k];
                acc[r].x += xv * cv.x; acc[r].y += xv * cv.y;
                acc[r].z += xv * cv.z; acc[r].w += xv * cv.w;
            }
        }
        const int w = t >> 6;
#pragma unroll
        for (int r = 0; r < 4; ++r) {
            const float4 mu = ((float4*)shbuf)[r * H4 + t];
            float pd = acc[r].x * mu.x + acc[r].y * mu.y + acc[r].z * mu.z + acc[r].w * mu.w;
#pragma unroll
            for (int off = 32; off > 0; off >>= 1) pd += __shfl_down(pd, off, 64);
            if ((t & 63) == 0) red[r][w] = pd;
        }
        __syncthreads();
        if (t < 4) {
            const int row = r0 + t;
            if (row < C)
                tm_part[ks * 152 + row] = red[t][0] + red[t][1] + red[t][2];
        }
    }
}

// ---------------------------------------------------------------------------
// kC: xS col-slice GEMM (pool-finalize inlined) + t_x partials + score-dot
// partials vs all 150 means. grid 512 = 64 row-tiles (4 rows) x 8 col-splits,
// block 192 = 8 kg x 24 f4-cols. ~17 KB LDS -> 2 blocks/CU resident.
// ---------------------------------------------------------------------------
__global__ __launch_bounds__(192) void kC(const float* __restrict__ part1,
                                          const int* __restrict__ cntp,
                                          const float* __restrict__ cov,
                                          const float* __restrict__ means,
                                          float* __restrict__ dp,
                                          float* __restrict__ tx_part) {
    const int rt = blockIdx.x >> 3, cs = blockIdx.x & 7;
    const int r0 = rt * 4, cb = cs * 24;
    const int t = threadIdx.x;
    const int kg = t / 24, c4 = t % 24;
    __shared__ float xsl[4 * H];          // 12 KB
    __shared__ float4 red2[8][24];        // 3 KB
    __shared__ float4 xsf[4][24];         // 1.5 KB

    // pool finalize into LDS
#pragma unroll
    for (int r = 0; r < 4; ++r) {
        const int row = r0 + r;
        const int cnt = cntp[row * 4] + cntp[row * 4 + 1] + cntp[row * 4 + 2] + cntp[row * 4 + 3];
        const float inv = 1.0f / fmaxf((float)cnt, 1e-9f);
        const float4* p = (const float4*)part1 + (size_t)row * 4 * H4 + t;
        const float4 a = p[0], b2 = p[H4], c2 = p[2 * H4], d2 = p[3 * H4];
        float4 v;
        v.x = (a.x + b2.x + c2.x + d2.x) * inv;
        v.y = (a.y + b2.y + c2.y + d2.y) * inv;
        v.z = (a.z + b2.z + c2.z + d2.z) * inv;
        v.w = (a.w + b2.w + c2.w + d2.w) * inv;
        ((float4*)xsl)[r * H4 + t] = v;
    }
    __syncthreads();

    float4 acc[4];
#pragma unroll
    for (int r = 0; r < 4; ++r) acc[r] = make_float4(0.f, 0.f, 0.f, 0.f);
    const float4* cov4 = (const float4*)cov + cb + c4;
#pragma unroll 4
    for (int kk = 0; kk < 96; ++kk) {
        const int k = kg * 96 + kk;
        const float4 cv = cov4[(size_t)k * H4];
#pragma unroll
        for (int r = 0; r < 4; ++r) {
            const float xv = xsl[r * H + k];
            acc[r].x += xv * cv.x; acc[r].y += xv * cv.y;
            acc[r].z += xv * cv.z; acc[r].w += xv * cv.w;
        }
    }

    float pdr[4];
#pragma unroll
    for (int r = 0; r < 4; ++r) pdr[r] = 0.f;
    for (int r = 0; r < 4; ++r) {
        red2[kg][c4] = acc[r];
        __syncthreads();
        if (kg == 0) {
            float4 s = red2[0][c4];
#pragma unroll
            for (int g = 1; g < 8; ++g) {
                const float4 q = red2[g][c4];
                s.x += q.x; s.y += q.y; s.z += q.z; s.w += q.w;
            }
            xsf[r][c4] = s;
            const float4 xv = ((float4*)xsl)[r * H4 + cb + c4];
            pdr[r] = s.x * xv.x + s.y * xv.y + s.z * xv.z + s.w * xv.w;
        }
        __syncthreads();
    }

    // t_x partials (lanes 0..23 hold contributions)
    if (t < 64) {
#pragma unroll
        for (int r = 0; r < 4; ++r) {
            float v = (t < 24) ? pdr[r] : 0.f;
#pragma unroll
            for (int off = 16; off > 0; off >>= 1) v += __shfl_down(v, off, 32);
            if (t == 0) tx_part[cs * 256 + r0 + r] = v;
        }
    }

    // score-dot partials: thread t = class c, stream means slice from L2
    if (t < C) {
        const float4* mu4 = (const float4*)means + (size_t)t * H4 + cb;
        float a8[4];
#pragma unroll
        for (int r = 0; r < 4; ++r) a8[r] = 0.f;
#pragma unroll 4
        for (int j = 0; j < 24; ++j) {
            const float4 mv = mu4[j];
#pragma unroll
            for (int r = 0; r < 4; ++r) {
                const float4 x = xsf[r][j];
                a8[r] += mv.x * x.x + mv.y * x.y + mv.z * x.z + mv.w * x.w;
            }
        }
#pragma unroll
        for (int r = 0; r < 4; ++r)
            dp[((size_t)(cs * 256) + (r0 + r)) * 150 + t] = a8[r];
    }
}

// ---------------------------------------------------------------------------
// kD: reduce partials -> scores + argmin. One block per b, 192 threads.
// ---------------------------------------------------------------------------
__global__ __launch_bounds__(192) void kD(const float* __restrict__ dp,
                                          const float* __restrict__ tx_part,
                                          const float* __restrict__ tm_part,
                                          float* __restrict__ out) {
    const int b = blockIdx.x, t = threadIdx.x;
    __shared__ float sv[192];
    __shared__ int si[192];

    float sc = INFINITY;
    if (t < C) {
        float d = 0.f;
#pragma unroll
        for (int j = 0; j < 8; ++j) d += dp[((size_t)(j * 256) + b) * 150 + t];
        float tx = 0.f;
#pragma unroll
        for (int j = 0; j < 8; ++j) tx += tx_part[j * 256 + b];
        float tm = 0.f;
#pragma unroll
        for (int j = 0; j < 8; ++j) tm += tm_part[j * 152 + t];
        sc = tx - 2.0f * d + tm;
        out[B + (size_t)t * B + b] = sc;
    }
    sv[t] = sc;
    si[t] = (t < C) ? t : 0x7fffffff;
    __syncthreads();
#pragma unroll
    for (int off = 96; off >= 3; off >>= 1) {
        if (t < off) {
            const float ov = sv[t + off];
            const int oi = si[t + off];
            if (ov < sv[t] || (ov == sv[t] && oi < si[t])) { sv[t] = ov; si[t] = oi; }
        }
        __syncthreads();
    }
    if (t == 0) {
        float bv = sv[0];
        int bi = si[0];
#pragma unroll
        for (int j = 1; j < 3; ++j)
            if (sv[j] < bv || (sv[j] == bv && si[j] < bi)) { bv = sv[j]; bi = si[j]; }
        out[b] = (float)bi;
    }
}

extern "C" void kernel_launch(void* const* d_in, const int* in_sizes, int n_in,
                              void* d_out, int out_size, void* d_ws, size_t ws_size,
                              hipStream_t stream) {
    const float* lhs   = (const float*)d_in[0];   // [B,S,H] f32
    const int*   mask  = (const int*)d_in[1];     // [B,S] i32
    const float* means = (const float*)d_in[2];   // [C,H] f32
    const float* cov   = (const float*)d_in[3];   // [H,H] f32
    float* out = (float*)d_out;
    char* ws = (char*)d_ws;

    float* part1   = (float*)(ws + 0);
    float* dp      = (float*)(ws + 3145728);
    float* tx_part = (float*)(ws + 4374528);
    float* tm_part = (float*)(ws + 4382720);
    int*   cntp    = (int*)  (ws + 4387584);

    kA<<<dim3(NTM + 1024), 192, 0, stream>>>(lhs, mask, means, cov, part1, cntp, tm_part);
    kC<<<dim3(512), 192, 0, stream>>>(part1, cntp, cov, means, dp, tx_part);
    kD<<<dim3(256), 192, 0, stream>>>(dp, tx_part, tm_part, out);
}

// Round 11
// 56.524 us; speedup vs baseline: 1.5537x; 1.0609x over previous
//
#include <hip/hip_runtime.h>
#include <hip/hip_bf16.h>

// Problem constants
#define B 256
#define S 256
#define H 768
#define C 150
#define H4 192              // H / 4 (float4 columns)

// ws layout (bytes):
//  prelogits : 0        .. 786432    [256][768] f32 (finalized pooled rows)
//  dp        : 786432   .. 2015232   [8][256][150] f32 score-dot partials
//  tx_part   : 2015232  .. 2023424   [8][256] f32
//  tm_part   : 2023424  .. 2028288   [8][152] f32

// ---------------------------------------------------------------------------
// kPool: one block per batch row b. 384 threads = 2 halves x 192 f4-cols;
// half h sums rows [h*128, h*128+128), halves combined via LDS, finalized
// (mask-count division) in-kernel -> writes prelogits directly.
// Grid 256 = exactly 1 block/CU: perfectly balanced, 6 waves/CU.
// ---------------------------------------------------------------------------
__global__ __launch_bounds__(384) void kPool(const float* __restrict__ lhs,
                                             const int* __restrict__ mask,
                                             float* __restrict__ prelogits) {
    const int b = blockIdx.x;
    const int t = threadIdx.x;
    const int h = t / H4, c4 = t - h * H4;   // half 0/1, f4-col 0..191
    __shared__ float msk[S];                 // 1 KB
    __shared__ float4 hbuf[H4];              // 3 KB
    __shared__ float cntsh;

    if (t < S) msk[t] = (float)mask[b * S + t];
    __syncthreads();

    // wave 5 computes the mask count while others start streaming
    if (t >= 320) {
        const int idx = t - 320;             // 0..63
        float v = msk[idx] + msk[idx + 64] + msk[idx + 128] + msk[idx + 192];
#pragma unroll
        for (int off = 32; off > 0; off >>= 1) v += __shfl_down(v, off, 64);
        if (idx == 0) cntsh = v;
    }

    const float4* src = (const float4*)lhs + (size_t)(b * S + h * 128) * H4 + c4;
    const float* mrow = msk + h * 128;
    float4 acc = make_float4(0.f, 0.f, 0.f, 0.f);
#pragma unroll 8
    for (int s = 0; s < 128; ++s) {
        const float m = mrow[s];
        const float4 v = src[(size_t)s * H4];
        acc.x += v.x * m; acc.y += v.y * m; acc.z += v.z * m; acc.w += v.w * m;
    }
    if (h == 1) hbuf[c4] = acc;
    __syncthreads();
    if (h == 0) {
        const float4 o = hbuf[c4];
        const float inv = 1.0f / fmaxf(cntsh, 1e-9f);
        float4 r;
        r.x = (acc.x + o.x) * inv;
        r.y = (acc.y + o.y) * inv;
        r.z = (acc.z + o.z) * inv;
        r.w = (acc.w + o.w) * inv;
        ((float4*)prelogits)[(size_t)b * H4 + c4] = r;
    }
}

// ---------------------------------------------------------------------------
// kC: blocks 0..255  : xS col-slice GEMM (prelogits read straight into LDS)
//                      + t_x partials + score-dot partials vs all 150 means.
//     blocks 256..407: t_m partials (means @ cov . means), no pool dependency.
// block 192 = 8 kg x 24 f4-cols.
// ---------------------------------------------------------------------------
__global__ __launch_bounds__(192) void kC(const float* __restrict__ prelogits,
                                          const float* __restrict__ cov,
                                          const float* __restrict__ means,
                                          float* __restrict__ dp,
                                          float* __restrict__ tx_part,
                                          float* __restrict__ tm_part) {
    const int t = threadIdx.x;
    const int kg = t / 24, c4 = t % 24;
    __shared__ float xsl[8 * H];          // 24 KB
    __shared__ float4 red2[8][24];        // 3 KB
    __shared__ float4 xsf[8][24];         // 3 KB
    __shared__ float sred[8][3];

    if (blockIdx.x < 256) {
        const int rt = blockIdx.x >> 3, cs = blockIdx.x & 7;
        const int r0 = rt * 8, cb = cs * 24;

        // load pooled rows into LDS (already finalized)
#pragma unroll
        for (int r = 0; r < 8; ++r)
            ((float4*)xsl)[r * H4 + t] = ((const float4*)prelogits)[(size_t)(r0 + r) * H4 + t];
        __syncthreads();

        float4 acc[8];
#pragma unroll
        for (int r = 0; r < 8; ++r) acc[r] = make_float4(0.f, 0.f, 0.f, 0.f);
        const float4* cov4 = (const float4*)cov + cb + c4;
#pragma unroll 4
        for (int kk = 0; kk < 96; ++kk) {
            const int k = kg * 96 + kk;
            const float4 cv = cov4[(size_t)k * H4];
#pragma unroll
            for (int r = 0; r < 8; ++r) {
                const float xv = xsl[r * H + k];
                acc[r].x += xv * cv.x; acc[r].y += xv * cv.y;
                acc[r].z += xv * cv.z; acc[r].w += xv * cv.w;
            }
        }

        float pdr[8];
#pragma unroll
        for (int r = 0; r < 8; ++r) pdr[r] = 0.f;
        for (int r = 0; r < 8; ++r) {
            red2[kg][c4] = acc[r];
            __syncthreads();
            if (kg == 0) {
                float4 s = red2[0][c4];
#pragma unroll
                for (int g = 1; g < 8; ++g) {
                    const float4 q = red2[g][c4];
                    s.x += q.x; s.y += q.y; s.z += q.z; s.w += q.w;
                }
                xsf[r][c4] = s;
                const float4 xv = ((float4*)xsl)[r * H4 + cb + c4];
                pdr[r] = s.x * xv.x + s.y * xv.y + s.z * xv.z + s.w * xv.w;
            }
            __syncthreads();
        }

        // t_x partials (lanes 0..23 hold contributions)
        if (t < 64) {
#pragma unroll
            for (int r = 0; r < 8; ++r) {
                float v = (t < 24) ? pdr[r] : 0.f;
#pragma unroll
                for (int off = 16; off > 0; off >>= 1) v += __shfl_down(v, off, 32);
                if (t == 0) tx_part[cs * 256 + r0 + r] = v;
            }
        }

        // score-dot partials: thread t = class c, stream means slice from L2
        if (t < C) {
            const float4* mu4 = (const float4*)means + (size_t)t * H4 + cb;
            float a8[8];
#pragma unroll
            for (int r = 0; r < 8; ++r) a8[r] = 0.f;
#pragma unroll 4
            for (int j = 0; j < 24; ++j) {
                const float4 mv = mu4[j];
#pragma unroll
                for (int r = 0; r < 8; ++r) {
                    const float4 x = xsf[r][j];
                    a8[r] += mv.x * x.x + mv.y * x.y + mv.z * x.z + mv.w * x.w;
                }
            }
#pragma unroll
            for (int r = 0; r < 8; ++r)
                dp[((size_t)(cs * 256) + (r0 + r)) * 150 + t] = a8[r];
        }
    } else {
        // ---- t_m partials: rows r0..r0+7 of means, f4-cols cb..cb+23, k-split 8 ----
        const int idx = blockIdx.x - 256;
        const int rt = idx >> 3, cs = idx & 7;
        const int r0 = rt * 8, cb = cs * 24;

        for (int r = 0; r < 8; ++r) {
            const int row = r0 + r;
            float4 v = make_float4(0.f, 0.f, 0.f, 0.f);
            if (row < C) v = ((const float4*)means)[(size_t)row * H4 + t];
            ((float4*)xsl)[r * H4 + t] = v;
        }
        __syncthreads();

        float4 acc[8];
#pragma unroll
        for (int r = 0; r < 8; ++r) acc[r] = make_float4(0.f, 0.f, 0.f, 0.f);
        const float4* cov4 = (const float4*)cov + cb + c4;
#pragma unroll 4
        for (int kk = 0; kk < 96; ++kk) {
            const int k = kg * 96 + kk;
            const float4 cv = cov4[(size_t)k * H4];
#pragma unroll
            for (int r = 0; r < 8; ++r) {
                const float xv = xsl[r * H + k];
                acc[r].x += xv * cv.x; acc[r].y += xv * cv.y;
                acc[r].z += xv * cv.z; acc[r].w += xv * cv.w;
            }
        }
        const int w = t >> 6;
#pragma unroll
        for (int r = 0; r < 8; ++r) {
            const float4 mu = ((float4*)xsl)[r * H4 + cb + c4];
            float pd = acc[r].x * mu.x + acc[r].y * mu.y + acc[r].z * mu.z + acc[r].w * mu.w;
#pragma unroll
            for (int off = 32; off > 0; off >>= 1) pd += __shfl_down(pd, off, 64);
            if ((t & 63) == 0) sred[r][w] = pd;
        }
        __syncthreads();
        if (t < 8) {
            const int row = r0 + t;
            if (row < C)
                tm_part[cs * 152 + row] = sred[t][0] + sred[t][1] + sred[t][2];
        }
    }
}

// ---------------------------------------------------------------------------
// kD: reduce partials -> scores + argmin. One block per b, 192 threads.
// ---------------------------------------------------------------------------
__global__ __launch_bounds__(192) void kD(const float* __restrict__ dp,
                                          const float* __restrict__ tx_part,
                                          const float* __restrict__ tm_part,
                                          float* __restrict__ out) {
    const int b = blockIdx.x, t = threadIdx.x;
    __shared__ float sv[192];
    __shared__ int si[192];

    float sc = INFINITY;
    if (t < C) {
        float d = 0.f;
#pragma unroll
        for (int j = 0; j < 8; ++j) d += dp[((size_t)(j * 256) + b) * 150 + t];
        float tx = 0.f;
#pragma unroll
        for (int j = 0; j < 8; ++j) tx += tx_part[j * 256 + b];
        float tm = 0.f;
#pragma unroll
        for (int j = 0; j < 8; ++j) tm += tm_part[j * 152 + t];
        sc = tx - 2.0f * d + tm;
        out[B + (size_t)t * B + b] = sc;
    }
    sv[t] = sc;
    si[t] = (t < C) ? t : 0x7fffffff;
    __syncthreads();
#pragma unroll
    for (int off = 96; off >= 3; off >>= 1) {
        if (t < off) {
            const float ov = sv[t + off];
            const int oi = si[t + off];
            if (ov < sv[t] || (ov == sv[t] && oi < si[t])) { sv[t] = ov; si[t] = oi; }
        }
        __syncthreads();
    }
    if (t == 0) {
        float bv = sv[0];
        int bi = si[0];
#pragma unroll
        for (int j = 1; j < 3; ++j)
            if (sv[j] < bv || (sv[j] == bv && si[j] < bi)) { bv = sv[j]; bi = si[j]; }
        out[b] = (float)bi;
    }
}

extern "C" void kernel_launch(void* const* d_in, const int* in_sizes, int n_in,
                              void* d_out, int out_size, void* d_ws, size_t ws_size,
                              hipStream_t stream) {
    const float* lhs   = (const float*)d_in[0];   // [B,S,H] f32
    const int*   mask  = (const int*)d_in[1];     // [B,S] i32
    const float* means = (const float*)d_in[2];   // [C,H] f32
    const float* cov   = (const float*)d_in[3];   // [H,H] f32
    float* out = (float*)d_out;
    char* ws = (char*)d_ws;

    float* prelogits = (float*)(ws + 0);
    float* dp        = (float*)(ws + 786432);
    float* tx_part   = (float*)(ws + 2015232);
    float* tm_part   = (float*)(ws + 2023424);

    kPool<<<dim3(B), 384, 0, stream>>>(lhs, mask, prelogits);
    kC<<<dim3(256 + 152), 192, 0, stream>>>(prelogits, cov, means, dp, tx_part, tm_part);
    kD<<<dim3(256), 192, 0, stream>>>(dp, tx_part, tm_part, out);
}